// Round 21
// baseline (25.409 us; speedup 1.0000x reference)
//
#include <hip/hip_runtime.h>
#include <hip/hip_bf16.h>
#include <math.h>

typedef short s16x8 __attribute__((ext_vector_type(8)));
typedef float f32x4 __attribute__((ext_vector_type(4)));

namespace {
constexpr int kB = 2;
constexpr int kT = 4096;
constexpr int kD = 512;          // GEMM K
constexpr int kH = 64;           // per-matrix N
constexpr int kRows = kB * kT;   // GEMM M = 8192

// workspace byte offsets
constexpr size_t oBH   = 0;                                   // W hi frag-major (192KB)
constexpr size_t oQKhi = oBH + (size_t)192 * 64 * 16;         // [8192][128] bf16 (Q|K)
constexpr size_t oVT   = oQKhi + (size_t)kRows * 128 * 2;     // [2][64][4096] bf16
// VT negative-index reads (t0<256, up to 512B back) land in QKhi: finite, times E=0.

constexpr int TQ = 16;           // queries per attn block
constexpr int SPADB = 296;       // bf16 E LDS row stride (cols 0..287 used)
}

__device__ __forceinline__ ushort bf16bits(float x) {
  __hip_bfloat16 hb = __float2bfloat16(x);            // RNE
  return *reinterpret_cast<ushort*>(&hb);
}

// ---------------------------------------------------------------------------
// Kernel 0: W -> hi bf16, MFMA-fragment-major. (unchanged)
// ---------------------------------------------------------------------------
__global__ __launch_bounds__(256) void prep_w(
    const float* __restrict__ Wq, const float* __restrict__ Wk,
    const float* __restrict__ Wv, s16x8* __restrict__ BH) {
  const int w = threadIdx.x >> 6;
  const int lane = threadIdx.x & 63;
  const int gw = blockIdx.x * 4 + w;   // 0..191
  const int ks = gw & 15;
  const int mn = gw >> 4;              // mat*4 + nf
  const int mat = mn >> 2;
  const int nf = mn & 3;
  const float* __restrict__ W = (mat == 0) ? Wq : (mat == 1) ? Wk : Wv;
  const int n = nf * 16 + (lane & 15);
  const int kb = ks * 32 + (lane >> 4) * 8;
  s16x8 vh;
#pragma unroll
  for (int e = 0; e < 8; ++e) vh[e] = (short)bf16bits(W[(size_t)(kb + e) * kH + n]);
  BH[(size_t)gw * 64 + lane] = vh;
}

// ---------------------------------------------------------------------------
// Kernel 1: fused QKV projection — pure bf16, BM=16 (R18 structure, best
// measured).
// ---------------------------------------------------------------------------
__global__ __launch_bounds__(256) void qkv_fused(
    const float* __restrict__ X, const s16x8* __restrict__ BH,
    ushort* __restrict__ QKhi, ushort* __restrict__ VT) {
  __shared__ ushort AHs[16][520];

  const int tid = threadIdx.x;
  const int mt = blockIdx.x;           // 0..511

  // ---- Phase 1: cooperative X -> bf16 into LDS ----
  const float* __restrict__ xb = X + (size_t)mt * 16 * kD;
#pragma unroll
  for (int it = 0; it < 8; ++it) {
    const int idx = tid + it * 256;    // 0..2047 float4-units
    const int row = idx >> 7;
    const int c4 = (idx & 127) * 4;
    const float4 x = *reinterpret_cast<const float4*>(xb + (size_t)row * kD + c4);
    ushort4 hi;
    hi.x = bf16bits(x.x);
    hi.y = bf16bits(x.y);
    hi.z = bf16bits(x.z);
    hi.w = bf16bits(x.w);
    *reinterpret_cast<ushort4*>(&AHs[row][c4]) = hi;
  }
  __syncthreads();

  // ---- Phase 2: MFMA (wave w -> n-tiles w*3..w*3+2) ----
  const int w = tid >> 6;
  const int lane = tid & 63;
  const int l15 = lane & 15;
  const int kcol = (lane >> 4) * 8;
  const int nt0 = w * 3;

  f32x4 acc0 = {0.f, 0.f, 0.f, 0.f};
  f32x4 acc1 = {0.f, 0.f, 0.f, 0.f};
  f32x4 acc2 = {0.f, 0.f, 0.f, 0.f};

#pragma unroll
  for (int ks = 0; ks < 16; ++ks) {
    const s16x8 ah = *reinterpret_cast<const s16x8*>(&AHs[l15][ks * 32 + kcol]);
    const s16x8 bh0 = BH[(size_t)((nt0 + 0) * 16 + ks) * 64 + lane];
    const s16x8 bh1 = BH[(size_t)((nt0 + 1) * 16 + ks) * 64 + lane];
    const s16x8 bh2 = BH[(size_t)((nt0 + 2) * 16 + ks) * 64 + lane];
    acc0 = __builtin_amdgcn_mfma_f32_16x16x32_bf16(ah, bh0, acc0, 0, 0, 0);
    acc1 = __builtin_amdgcn_mfma_f32_16x16x32_bf16(ah, bh1, acc1, 0, 0, 0);
    acc2 = __builtin_amdgcn_mfma_f32_16x16x32_bf16(ah, bh2, acc2, 0, 0, 0);
  }

  // write-back: C row = mt*16 + (lane>>4)*4 + r, C col = nt*16 + l15
  const int r0 = (lane >> 4) * 4;
  f32x4 accs[3] = {acc0, acc1, acc2};
#pragma unroll
  for (int j = 0; j < 3; ++j) {
    const int colg = (nt0 + j) * 16 + l15;   // 0..191
    if (colg < 128) {
#pragma unroll
      for (int r = 0; r < 4; ++r)
        QKhi[(size_t)(mt * 16 + r0 + r) * 128 + colg] = bf16bits(accs[j][r]);
    } else {
      const int colv = colg - 128;
      const int mrow0 = mt * 16 + r0;
      const int b = mrow0 >> 12;
      const int t = mrow0 & (kT - 1);
      ushort4 pk;
      pk.x = bf16bits(accs[j][0]);
      pk.y = bf16bits(accs[j][1]);
      pk.z = bf16bits(accs[j][2]);
      pk.w = bf16bits(accs[j][3]);
      *reinterpret_cast<ushort4*>(VT + (size_t)(b * kH + colv) * kT + t) = pk;
    }
  }
}

// ---------------------------------------------------------------------------
// Kernel 2: sliding-window attention — single-barrier structure.
// (1) V fragments prefetched into registers at kernel start (independent of
//     all in-kernel writes) -> their L2 latency hides under QK+exp.
// (2) Row-sums folded into the exp phase via in-register 4-bit shfl_xor
//     reduce -> wsum[4][16] partials (no 18-load sum pass).
// (3) Normalization deferred to the epilogue (reads wsum after PV MFMAs)
//     -> second __syncthreads eliminated.
// ---------------------------------------------------------------------------
__global__ __launch_bounds__(256, 2) void swin_attn(
    const ushort* __restrict__ QKhi, const ushort* __restrict__ VT,
    float* __restrict__ O) {
  __shared__ ushort PSm[TQ][SPADB];     // bf16 E, cols 0..287 (272..287 zeroed)
  __shared__ float wsum[4][TQ];         // per-wave row partial sums

  const int tid = threadIdx.x;
  const int w = tid >> 6;
  const int lane = tid & 63;
  // bijective XCD-chunk swizzle: 512 = 8 XCDs x 64 consecutive tiles
  const int bi = (blockIdx.x & 7) * 64 + (blockIdx.x >> 3);
  const int row0 = bi * TQ;
  const int t0 = row0 & (kT - 1);
  const int b = row0 >> 12;

  const int l15 = lane & 15;
  const int kcol = (lane >> 4) * 8;

  // zero tail cols 272..287 (PV reads 288 cols; tile 17 region unwritten)
  PSm[tid >> 4][272 + (tid & 15)] = 0;

  // ---- prefetch V fragments (independent of all in-kernel writes) ----
  const int hcol = w * 16 + l15;
  const ushort* vt = VT + (size_t)(b * kH + hcol) * kT + t0 - 256;
  s16x8 vbf[9];
#pragma unroll
  for (int kt = 0; kt < 9; ++kt)
    vbf[kt] = *reinterpret_cast<const s16x8*>(vt + kt * 32 + kcol);

  // ---- Q fragments (hi only): m = l15, k = kt*32 + kcol + e ----
  s16x8 qh[2];
  {
    const ushort* qp = QKhi + (size_t)(row0 + l15) * 128 + kcol;
#pragma unroll
    for (int kt = 0; kt < 2; ++kt)
      qh[kt] = *reinterpret_cast<const s16x8*>(qp + kt * 32);
  }

  // ---- QK^T over 17 tiles: wave w -> tiles w*4..w*4+3 (+16 for w==3) ----
  f32x4 acc[5];
#pragma unroll
  for (int i = 0; i < 5; ++i) acc[i] = (f32x4){0.f, 0.f, 0.f, 0.f};

  const int NT = (w == 3) ? 5 : 4;
#pragma unroll
  for (int nt5 = 0; nt5 < 5; ++nt5) {
    if (nt5 < NT) {
      const int nt = w * 4 + nt5;      // w==3,nt5==4 -> 16
      const int p = t0 - 256 + nt * 16 + l15;
      const int pc = min(max(p, 0), kT - 1);   // invalid slots masked below
      const ushort* kp = QKhi + ((size_t)(b * kT + pc)) * 128 + 64 + kcol;
#pragma unroll
      for (int kt = 0; kt < 2; ++kt) {
        const s16x8 khh = *reinterpret_cast<const s16x8*>(kp + kt * 32);
        acc[nt5] = __builtin_amdgcn_mfma_f32_16x16x32_bf16(qh[kt], khh, acc[nt5], 0, 0, 0);
      }
    }
  }

  // ---- masked exp -> PSm (bf16) + in-register row partial sums ----
  float rsum[4] = {0.f, 0.f, 0.f, 0.f};   // rows (lane>>4)*4 + r
#pragma unroll
  for (int nt5 = 0; nt5 < 5; ++nt5) {
    if (nt5 < NT) {
      const int nt = w * 4 + nt5;
      const int jg = nt * 16 + l15;
      const int p = t0 - 256 + jg;
#pragma unroll
      for (int r = 0; r < 4; ++r) {
        const int i = (lane >> 4) * 4 + r;
        const int t = t0 + i;
        const int jref = p - t + 255;
        const bool valid = (p >= 0) && (jref >= 0) && (jref <= 255) && (jref <= t);
        const float e = valid ? __expf(acc[nt5][r] * 0.125f) : 0.f;
        PSm[i][jg] = bf16bits(e);
        rsum[r] += e;
      }
    }
  }
  // reduce rsum over the 16 lanes of each l15-group (bits 0..3)
#pragma unroll
  for (int r = 0; r < 4; ++r) {
#pragma unroll
    for (int off = 1; off < 16; off <<= 1) rsum[r] += __shfl_xor(rsum[r], off);
  }
  if (l15 == 0) {
#pragma unroll
    for (int r = 0; r < 4; ++r) wsum[w][(lane >> 4) * 4 + r] = rsum[r];
  }
  __syncthreads();

  // ---- PV: wave w covers h-columns w*16..w*16+15; 9 k-tiles (288 keys) ----
  f32x4 oacc = {0.f, 0.f, 0.f, 0.f};
#pragma unroll
  for (int kt = 0; kt < 9; ++kt) {
    const s16x8 pa = *reinterpret_cast<const s16x8*>(&PSm[l15][kt * 32 + kcol]);
    oacc = __builtin_amdgcn_mfma_f32_16x16x32_bf16(pa, vbf[kt], oacc, 0, 0, 0);
  }

  // ---- epilogue: combine wave partial sums + analytic pad term ----
#pragma unroll
  for (int r = 0; r < 4; ++r) {
    const int i = (lane >> 4) * 4 + r;
    const int t = t0 + i;
    const int n0 = (t < 255) ? min(t + 1, 255 - t) : 0;
    const float sum = (wsum[0][i] + wsum[1][i]) + (wsum[2][i] + wsum[3][i]) + (float)n0;
    O[(size_t)(row0 + i) * kH + hcol] = oacc[r] / sum;
  }
}

// ---------------------------------------------------------------------------
extern "C" void kernel_launch(void* const* d_in, const int* in_sizes, int n_in,
                              void* d_out, int out_size, void* d_ws, size_t ws_size,
                              hipStream_t stream) {
  const float* X  = (const float*)d_in[0];
  const float* Wq = (const float*)d_in[1];
  const float* Wk = (const float*)d_in[2];
  const float* Wv = (const float*)d_in[3];
  char* ws = (char*)d_ws;
  s16x8* BH = (s16x8*)(ws + oBH);
  ushort* QKhi = (ushort*)(ws + oQKhi);
  ushort* VT = (ushort*)(ws + oVT);
  float* O = (float*)d_out;

  prep_w<<<48, 256, 0, stream>>>(Wq, Wk, Wv, BH);
  qkv_fused<<<512, 256, 0, stream>>>(X, BH, QKhi, VT);
  swin_attn<<<512, 256, 0, stream>>>(QKhi, VT, O);
}

// Round 24
// 25.174 us; speedup vs baseline: 1.0093x; 1.0093x over previous
//
#include <hip/hip_runtime.h>
#include <hip/hip_bf16.h>
#include <math.h>

typedef short s16x8 __attribute__((ext_vector_type(8)));
typedef float f32x4 __attribute__((ext_vector_type(4)));

namespace {
constexpr int kB = 2;
constexpr int kT = 4096;
constexpr int kD = 512;          // GEMM K
constexpr int kH = 64;           // per-matrix N
constexpr int kRows = kB * kT;   // GEMM M = 8192

// workspace byte offsets
constexpr size_t oBH   = 0;                                   // W hi frag-major (192KB)
constexpr size_t oQKhi = oBH + (size_t)192 * 64 * 16;         // [8192][128] bf16 (Q|K)
constexpr size_t oVT   = oQKhi + (size_t)kRows * 128 * 2;     // [2][64][4096] bf16
// VT negative-index reads (t0<256, up to 512B back) land in QKhi: finite, times E=0.

constexpr int TQ = 16;           // queries per attn block
constexpr int SPADB = 296;       // bf16 E LDS row stride (cols 0..287 used)
}

__device__ __forceinline__ ushort bf16bits(float x) {
  __hip_bfloat16 hb = __float2bfloat16(x);            // RNE
  return *reinterpret_cast<ushort*>(&hb);
}

// ---------------------------------------------------------------------------
// Kernel 0: W -> hi bf16, MFMA-fragment-major. (unchanged)
// ---------------------------------------------------------------------------
__global__ __launch_bounds__(256) void prep_w(
    const float* __restrict__ Wq, const float* __restrict__ Wk,
    const float* __restrict__ Wv, s16x8* __restrict__ BH) {
  const int w = threadIdx.x >> 6;
  const int lane = threadIdx.x & 63;
  const int gw = blockIdx.x * 4 + w;   // 0..191
  const int ks = gw & 15;
  const int mn = gw >> 4;              // mat*4 + nf
  const int mat = mn >> 2;
  const int nf = mn & 3;
  const float* __restrict__ W = (mat == 0) ? Wq : (mat == 1) ? Wk : Wv;
  const int n = nf * 16 + (lane & 15);
  const int kb = ks * 32 + (lane >> 4) * 8;
  s16x8 vh;
#pragma unroll
  for (int e = 0; e < 8; ++e) vh[e] = (short)bf16bits(W[(size_t)(kb + e) * kH + n]);
  BH[(size_t)gw * 64 + lane] = vh;
}

// ---------------------------------------------------------------------------
// Kernel 1: fused QKV projection — BM=32 with 512 THREADS (8 waves).
// R19's BM=32 failed because 256 threads did 2x fill work; here per-thread
// fill is identical to R18 (8 float4). Waves (msub=0,1) sharing an nt-group
// read the SAME BH lines on the same CU -> second read is an L1 hit,
// halving the 100MB B L2-stream (the qkv kernel's modeled floor).
// ---------------------------------------------------------------------------
__global__ __launch_bounds__(512) void qkv_fused(
    const float* __restrict__ X, const s16x8* __restrict__ BH,
    ushort* __restrict__ QKhi, ushort* __restrict__ VT) {
  __shared__ ushort AHs[32][520];

  const int tid = threadIdx.x;
  const int mt = blockIdx.x;           // 0..255 (32-row tile)

  // ---- Phase 1: cooperative X -> bf16 into LDS (8 float4 per thread) ----
  const float* __restrict__ xb = X + (size_t)mt * 32 * kD;
#pragma unroll
  for (int it = 0; it < 8; ++it) {
    const int idx = tid + it * 512;    // 0..4095 float4-units
    const int row = idx >> 7;
    const int c4 = (idx & 127) * 4;
    const float4 x = *reinterpret_cast<const float4*>(xb + (size_t)row * kD + c4);
    ushort4 hi;
    hi.x = bf16bits(x.x);
    hi.y = bf16bits(x.y);
    hi.z = bf16bits(x.z);
    hi.w = bf16bits(x.w);
    *reinterpret_cast<ushort4*>(&AHs[row][c4]) = hi;
  }
  __syncthreads();

  // ---- Phase 2: MFMA. wave w: msub = w>>2 (row half), nt0 = (w&3)*3 ----
  const int w = tid >> 6;
  const int lane = tid & 63;
  const int l15 = lane & 15;
  const int kcol = (lane >> 4) * 8;
  const int msub = w >> 2;
  const int nt0 = (w & 3) * 3;

  f32x4 acc0 = {0.f, 0.f, 0.f, 0.f};
  f32x4 acc1 = {0.f, 0.f, 0.f, 0.f};
  f32x4 acc2 = {0.f, 0.f, 0.f, 0.f};

#pragma unroll
  for (int ks = 0; ks < 16; ++ks) {
    const s16x8 ah = *reinterpret_cast<const s16x8*>(&AHs[msub * 16 + l15][ks * 32 + kcol]);
    const s16x8 bh0 = BH[(size_t)((nt0 + 0) * 16 + ks) * 64 + lane];
    const s16x8 bh1 = BH[(size_t)((nt0 + 1) * 16 + ks) * 64 + lane];
    const s16x8 bh2 = BH[(size_t)((nt0 + 2) * 16 + ks) * 64 + lane];
    acc0 = __builtin_amdgcn_mfma_f32_16x16x32_bf16(ah, bh0, acc0, 0, 0, 0);
    acc1 = __builtin_amdgcn_mfma_f32_16x16x32_bf16(ah, bh1, acc1, 0, 0, 0);
    acc2 = __builtin_amdgcn_mfma_f32_16x16x32_bf16(ah, bh2, acc2, 0, 0, 0);
  }

  // write-back: C row = mt*32 + msub*16 + (lane>>4)*4 + r, C col = nt*16 + l15
  const int r0 = (lane >> 4) * 4;
  const int mrow0 = mt * 32 + msub * 16 + r0;
  f32x4 accs[3] = {acc0, acc1, acc2};
#pragma unroll
  for (int j = 0; j < 3; ++j) {
    const int colg = (nt0 + j) * 16 + l15;   // 0..191
    if (colg < 128) {
#pragma unroll
      for (int r = 0; r < 4; ++r)
        QKhi[(size_t)(mrow0 + r) * 128 + colg] = bf16bits(accs[j][r]);
    } else {
      const int colv = colg - 128;
      const int b = mrow0 >> 12;
      const int t = mrow0 & (kT - 1);
      ushort4 pk;
      pk.x = bf16bits(accs[j][0]);
      pk.y = bf16bits(accs[j][1]);
      pk.z = bf16bits(accs[j][2]);
      pk.w = bf16bits(accs[j][3]);
      *reinterpret_cast<ushort4*>(VT + (size_t)(b * kH + colv) * kT + t) = pk;
    }
  }
}

// ---------------------------------------------------------------------------
// Kernel 2: sliding-window attention — single-barrier structure (R21).
// ---------------------------------------------------------------------------
__global__ __launch_bounds__(256, 2) void swin_attn(
    const ushort* __restrict__ QKhi, const ushort* __restrict__ VT,
    float* __restrict__ O) {
  __shared__ ushort PSm[TQ][SPADB];     // bf16 E, cols 0..287 (272..287 zeroed)
  __shared__ float wsum[4][TQ];         // per-wave row partial sums

  const int tid = threadIdx.x;
  const int w = tid >> 6;
  const int lane = tid & 63;
  // bijective XCD-chunk swizzle: 512 = 8 XCDs x 64 consecutive tiles
  const int bi = (blockIdx.x & 7) * 64 + (blockIdx.x >> 3);
  const int row0 = bi * TQ;
  const int t0 = row0 & (kT - 1);
  const int b = row0 >> 12;

  const int l15 = lane & 15;
  const int kcol = (lane >> 4) * 8;

  // zero tail cols 272..287 (PV reads 288 cols; tile 17 region unwritten)
  PSm[tid >> 4][272 + (tid & 15)] = 0;

  // ---- prefetch V fragments (independent of all in-kernel writes) ----
  const int hcol = w * 16 + l15;
  const ushort* vt = VT + (size_t)(b * kH + hcol) * kT + t0 - 256;
  s16x8 vbf[9];
#pragma unroll
  for (int kt = 0; kt < 9; ++kt)
    vbf[kt] = *reinterpret_cast<const s16x8*>(vt + kt * 32 + kcol);

  // ---- Q fragments (hi only): m = l15, k = kt*32 + kcol + e ----
  s16x8 qh[2];
  {
    const ushort* qp = QKhi + (size_t)(row0 + l15) * 128 + kcol;
#pragma unroll
    for (int kt = 0; kt < 2; ++kt)
      qh[kt] = *reinterpret_cast<const s16x8*>(qp + kt * 32);
  }

  // ---- QK^T over 17 tiles: wave w -> tiles w*4..w*4+3 (+16 for w==3) ----
  f32x4 acc[5];
#pragma unroll
  for (int i = 0; i < 5; ++i) acc[i] = (f32x4){0.f, 0.f, 0.f, 0.f};

  const int NT = (w == 3) ? 5 : 4;
#pragma unroll
  for (int nt5 = 0; nt5 < 5; ++nt5) {
    if (nt5 < NT) {
      const int nt = w * 4 + nt5;      // w==3,nt5==4 -> 16
      const int p = t0 - 256 + nt * 16 + l15;
      const int pc = min(max(p, 0), kT - 1);   // invalid slots masked below
      const ushort* kp = QKhi + ((size_t)(b * kT + pc)) * 128 + 64 + kcol;
#pragma unroll
      for (int kt = 0; kt < 2; ++kt) {
        const s16x8 khh = *reinterpret_cast<const s16x8*>(kp + kt * 32);
        acc[nt5] = __builtin_amdgcn_mfma_f32_16x16x32_bf16(qh[kt], khh, acc[nt5], 0, 0, 0);
      }
    }
  }

  // ---- masked exp -> PSm (bf16) + in-register row partial sums ----
  float rsum[4] = {0.f, 0.f, 0.f, 0.f};   // rows (lane>>4)*4 + r
#pragma unroll
  for (int nt5 = 0; nt5 < 5; ++nt5) {
    if (nt5 < NT) {
      const int nt = w * 4 + nt5;
      const int jg = nt * 16 + l15;
      const int p = t0 - 256 + jg;
#pragma unroll
      for (int r = 0; r < 4; ++r) {
        const int i = (lane >> 4) * 4 + r;
        const int t = t0 + i;
        const int jref = p - t + 255;
        const bool valid = (p >= 0) && (jref >= 0) && (jref <= 255) && (jref <= t);
        const float e = valid ? __expf(acc[nt5][r] * 0.125f) : 0.f;
        PSm[i][jg] = bf16bits(e);
        rsum[r] += e;
      }
    }
  }
  // reduce rsum over the 16 lanes of each l15-group (bits 0..3)
#pragma unroll
  for (int r = 0; r < 4; ++r) {
#pragma unroll
    for (int off = 1; off < 16; off <<= 1) rsum[r] += __shfl_xor(rsum[r], off);
  }
  if (l15 == 0) {
#pragma unroll
    for (int r = 0; r < 4; ++r) wsum[w][(lane >> 4) * 4 + r] = rsum[r];
  }
  __syncthreads();

  // ---- PV: wave w covers h-columns w*16..w*16+15; 9 k-tiles (288 keys) ----
  f32x4 oacc = {0.f, 0.f, 0.f, 0.f};
#pragma unroll
  for (int kt = 0; kt < 9; ++kt) {
    const s16x8 pa = *reinterpret_cast<const s16x8*>(&PSm[l15][kt * 32 + kcol]);
    oacc = __builtin_amdgcn_mfma_f32_16x16x32_bf16(pa, vbf[kt], oacc, 0, 0, 0);
  }

  // ---- epilogue: combine wave partial sums + analytic pad term ----
#pragma unroll
  for (int r = 0; r < 4; ++r) {
    const int i = (lane >> 4) * 4 + r;
    const int t = t0 + i;
    const int n0 = (t < 255) ? min(t + 1, 255 - t) : 0;
    const float sum = (wsum[0][i] + wsum[1][i]) + (wsum[2][i] + wsum[3][i]) + (float)n0;
    O[(size_t)(row0 + i) * kH + hcol] = oacc[r] / sum;
  }
}

// ---------------------------------------------------------------------------
extern "C" void kernel_launch(void* const* d_in, const int* in_sizes, int n_in,
                              void* d_out, int out_size, void* d_ws, size_t ws_size,
                              hipStream_t stream) {
  const float* X  = (const float*)d_in[0];
  const float* Wq = (const float*)d_in[1];
  const float* Wk = (const float*)d_in[2];
  const float* Wv = (const float*)d_in[3];
  char* ws = (char*)d_ws;
  s16x8* BH = (s16x8*)(ws + oBH);
  ushort* QKhi = (ushort*)(ws + oQKhi);
  ushort* VT = (ushort*)(ws + oVT);
  float* O = (float*)d_out;

  prep_w<<<48, 256, 0, stream>>>(Wq, Wk, Wv, BH);
  qkv_fused<<<256, 512, 0, stream>>>(X, BH, QKhi, VT);
  swin_attn<<<512, 256, 0, stream>>>(QKhi, VT, O);
}